// Round 4
// baseline (251.468 us; speedup 1.0000x reference)
//
#include <hip/hip_runtime.h>
#include <hip/hip_bf16.h>
#include <cmath>

typedef float f32x4 __attribute__((ext_vector_type(4)));
typedef float f32x16 __attribute__((ext_vector_type(16)));
typedef __bf16 bf16x4 __attribute__((ext_vector_type(4)));
typedef __bf16 bf16x8 __attribute__((ext_vector_type(8)));

#define C_IN 384
#define C_OUT 384
#define SPB 4096      // spatial per batch image (64*64)
#define NPIX 131072   // 32 * 4096 total pixels
#define BPX 32        // pixels per block
#define ROWW 40       // LDS row stride in bf16 (80 B; word-stride 20 -> conflict-free b128 class)

// ---------------------------------------------------------------------------
// Kernel 1: fold LN affine into the weights.
//   Wp[o][c] = bf16(W[o][c] * gamma[c]);  t1[o] = sum_c float(Wp[o][c]);
//   t2[o] = sum_c beta[c]*W[o][c] + b[o]
// ---------------------------------------------------------------------------
__global__ __launch_bounds__(128) void ppl_prep_kernel(const float* __restrict__ W,
                                                       const float* __restrict__ gamma,
                                                       const float* __restrict__ beta,
                                                       const float* __restrict__ bias,
                                                       __bf16* __restrict__ Wp,
                                                       float* __restrict__ t1,
                                                       float* __restrict__ t2) {
  const int o = blockIdx.x;
  const int t = threadIdx.x;
  const float* row = W + o * C_IN;
  float s1 = 0.f, s2 = 0.f;
  for (int c = t; c < C_IN; c += 128) {
    const float w = row[c];
    const __bf16 wq = (__bf16)(w * gamma[c]);
    Wp[o * C_IN + c] = wq;
    s1 += (float)wq;
    s2 += beta[c] * w;
  }
#pragma unroll
  for (int off = 32; off > 0; off >>= 1) {
    s1 += __shfl_down(s1, off);
    s2 += __shfl_down(s2, off);
  }
  __shared__ float red[2][2];
  if ((t & 63) == 0) { red[t >> 6][0] = s1; red[t >> 6][1] = s2; }
  __syncthreads();
  if (t == 0) {
    t1[o] = red[0][0] + red[1][0];
    t2[o] = red[0][1] + red[1][1] + bias[o];
  }
}

// fast GELU: tanh-form via sigmoid, err <= ~1e-3 (validated R2: absmax unchanged)
__device__ __forceinline__ float gelu_fast(float v) {
  const float u = 0.7978845608028654f * v * __builtin_fmaf(0.044715f * v, v, 1.0f);
  const float e = __expf(-2.0f * u);
  return v * __builtin_amdgcn_rcpf(1.0f + e);
}

// ---------------------------------------------------------------------------
// Kernel 2: fused stats + GEMM + LN epilogue + GELU, fine-grained k-pipeline.
//   Block = 32 pixels x all 384 outs (4 waves, one 96-out quarter each).
//   12 iters of BK=32: double-buffered LDS X-slice, stage loads issued ~2.5
//   iters ahead (regs), cvt+stats+ds_write 1 iter ahead, W frags from L2.
//   Stats (fp32 sum/sumsq) accumulate during staging; reduced before epilogue.
// ---------------------------------------------------------------------------
__global__ __launch_bounds__(256, 4) void ppl_fused_kernel(const float* __restrict__ x,
                                                           const __bf16* __restrict__ Wp,
                                                           const float* __restrict__ t1g,
                                                           const float* __restrict__ t2g,
                                                           float* __restrict__ out) {
  __shared__ __bf16 Xs[2][BPX * ROWW];   // 2 x 2560 B
  __shared__ float sred_s[8][BPX];
  __shared__ float sred_q[8][BPX];
  __shared__ float mu_s[BPX];
  __shared__ float rs_s[BPX];

  const int tid = threadIdx.x;
  const int w = tid >> 6;        // wave id: out quarter
  const int lane = tid & 63;
  const int col = lane & 31;
  const int hi = lane >> 5;
  const int px = tid & 31;       // staging: pixel
  const int ks = tid >> 5;       // staging: k-slot 0..7
  const int p0 = blockIdx.x * BPX;
  const int b = p0 >> 12;
  const int s0 = p0 & 4095;
  const int ob = w * 96;

  const float* xks = x + (size_t)b * (C_IN * SPB) + s0 + px + (size_t)(ks * 4) * SPB;
  const __bf16* wpa = Wp + (size_t)(ob + col) * C_IN + hi * 8;

  float stA[4], stB[4];
  float ssum = 0.f, sqsum = 0.f;

  f32x16 acc[3];
#pragma unroll
  for (int n = 0; n < 3; ++n)
#pragma unroll
    for (int r = 0; r < 16; ++r) acc[n][r] = 0.f;

#define ISSUE(st, K)                                  \
  {                                                   \
    const float* xp_ = xks + (size_t)(K) * SPB;       \
    st[0] = xp_[0];                                   \
    st[1] = xp_[SPB];                                 \
    st[2] = xp_[2 * SPB];                             \
    st[3] = xp_[3 * SPB];                             \
  }

#define WRITEBUF(bi, st)                                        \
  {                                                             \
    bf16x4 pk_;                                                 \
    pk_[0] = (__bf16)st[0];                                     \
    pk_[1] = (__bf16)st[1];                                     \
    pk_[2] = (__bf16)st[2];                                     \
    pk_[3] = (__bf16)st[3];                                     \
    ssum += st[0] + st[1] + st[2] + st[3];                      \
    sqsum += st[0] * st[0] + st[1] * st[1] + st[2] * st[2] + st[3] * st[3]; \
    *reinterpret_cast<bf16x4*>(&Xs[bi][px * ROWW + ks * 4]) = pk_; \
  }

#define COMPUTE(bi, K)                                                            \
  {                                                                               \
    const bf16x8 a0_ = *reinterpret_cast<const bf16x8*>(&Xs[bi][col * ROWW + hi * 8]);      \
    const bf16x8 a1_ = *reinterpret_cast<const bf16x8*>(&Xs[bi][col * ROWW + 16 + hi * 8]); \
    const bf16x8 b00_ = *reinterpret_cast<const bf16x8*>(wpa + (K));              \
    const bf16x8 b01_ = *reinterpret_cast<const bf16x8*>(wpa + 32 * C_IN + (K));  \
    const bf16x8 b02_ = *reinterpret_cast<const bf16x8*>(wpa + 64 * C_IN + (K));  \
    const bf16x8 b10_ = *reinterpret_cast<const bf16x8*>(wpa + (K) + 16);         \
    const bf16x8 b11_ = *reinterpret_cast<const bf16x8*>(wpa + 32 * C_IN + (K) + 16); \
    const bf16x8 b12_ = *reinterpret_cast<const bf16x8*>(wpa + 64 * C_IN + (K) + 16); \
    acc[0] = __builtin_amdgcn_mfma_f32_32x32x16_bf16(a0_, b00_, acc[0], 0, 0, 0); \
    acc[1] = __builtin_amdgcn_mfma_f32_32x32x16_bf16(a0_, b01_, acc[1], 0, 0, 0); \
    acc[2] = __builtin_amdgcn_mfma_f32_32x32x16_bf16(a0_, b02_, acc[2], 0, 0, 0); \
    acc[0] = __builtin_amdgcn_mfma_f32_32x32x16_bf16(a1_, b10_, acc[0], 0, 0, 0); \
    acc[1] = __builtin_amdgcn_mfma_f32_32x32x16_bf16(a1_, b11_, acc[1], 0, 0, 0); \
    acc[2] = __builtin_amdgcn_mfma_f32_32x32x16_bf16(a1_, b12_, acc[2], 0, 0, 0); \
  }

  // ---- prologue: fill the pipeline ----
  ISSUE(stA, 0);       // iter 0 data
  ISSUE(stB, 32);      // iter 1 data
  WRITEBUF(0, stA);    // buf0 <- iter 0
  ISSUE(stA, 64);      // iter 2 data
  __syncthreads();

  // ---- main k-loop: even iters consume stB, odd consume stA ----
#pragma unroll
  for (int i = 0; i < 12; ++i) {
    const int K = i * 32;
    COMPUTE(i & 1, K);
    if (i < 11) {
      if (i & 1) {
        WRITEBUF((i + 1) & 1, stA);
        if (i + 3 < 12) ISSUE(stA, (i + 3) * 32);
      } else {
        WRITEBUF((i + 1) & 1, stB);
        if (i + 3 < 12) ISSUE(stB, (i + 3) * 32);
      }
      __syncthreads();
    }
  }
#undef ISSUE
#undef WRITEBUF
#undef COMPUTE

  // ---- LN stats reduce (8 k-slots per pixel) ----
  sred_s[ks][px] = ssum;
  sred_q[ks][px] = sqsum;
  __syncthreads();
  if (tid < BPX) {
    float st = 0.f, qt = 0.f;
#pragma unroll
    for (int r = 0; r < 8; ++r) {
      st += sred_s[r][tid];
      qt += sred_q[r][tid];
    }
    const float m = st * (1.0f / C_IN);
    mu_s[tid] = m;
    rs_s[tid] = rsqrtf(qt * (1.0f / C_IN) - m * m + 1e-5f);
  }
  __syncthreads();

  // ---- epilogue: LN correction + GELU + float4 NCHW stores ----
  const float t1v[3] = {t1g[ob + col], t1g[ob + 32 + col], t1g[ob + 64 + col]};
  const float t2v[3] = {t2g[ob + col], t2g[ob + 32 + col], t2g[ob + 64 + col]};
  float* outp = out + (((size_t)(b * C_OUT + ob + col)) << 12) + s0;

#pragma unroll
  for (int nf = 0; nf < 3; ++nf) {
    float* op = outp + ((size_t)nf << 17);  // += 32 out-channels
#pragma unroll
    for (int qd = 0; qd < 4; ++qd) {
      const int pr = qd * 8 + hi * 4;  // pixel base of this reg quad
      const f32x4 mu4 = *reinterpret_cast<const f32x4*>(&mu_s[pr]);
      const f32x4 rs4 = *reinterpret_cast<const f32x4*>(&rs_s[pr]);
      f32x4 y;
#pragma unroll
      for (int r = 0; r < 4; ++r) {
        const float val = rs4[r] * (acc[nf][qd * 4 + r] - mu4[r] * t1v[nf]) + t2v[nf];
        y[r] = gelu_fast(val);
      }
      *reinterpret_cast<f32x4*>(op + pr) = y;
    }
  }
}

// ---------------------------------------------------------------------------
extern "C" void kernel_launch(void* const* d_in, const int* in_sizes, int n_in,
                              void* d_out, int out_size, void* d_ws, size_t ws_size,
                              hipStream_t stream) {
  const float* x = (const float*)d_in[0];
  const float* gamma = (const float*)d_in[1];
  const float* beta = (const float*)d_in[2];
  const float* W = (const float*)d_in[3];
  const float* bias = (const float*)d_in[4];
  float* out = (float*)d_out;

  __bf16* Wp = (__bf16*)d_ws;                    // 384*384 bf16
  float* t1 = (float*)(Wp + C_OUT * C_IN);       // 384 floats
  float* t2 = t1 + C_OUT;                        // 384 floats

  ppl_prep_kernel<<<C_OUT, 128, 0, stream>>>(W, gamma, beta, bias, Wp, t1, t2);
  ppl_fused_kernel<<<NPIX / BPX, 256, 0, stream>>>(x, Wp, t1, t2, out);
}

// Round 5
// 176.481 us; speedup vs baseline: 1.4249x; 1.4249x over previous
//
#include <hip/hip_runtime.h>
#include <hip/hip_bf16.h>
#include <cmath>

typedef float f32x4 __attribute__((ext_vector_type(4)));
typedef float f32x16 __attribute__((ext_vector_type(16)));
typedef __bf16 bf16x4 __attribute__((ext_vector_type(4)));
typedef __bf16 bf16x8 __attribute__((ext_vector_type(8)));

#define C_IN 384
#define C_OUT 384
#define SPB 4096      // spatial per batch image (64*64)
#define NPIX 131072   // 32 * 4096 total pixels
#define BP 64         // pixels per block
#define LDK 392       // padded Xs row (bf16): 784 B, 16B-aligned; measured 0 read conflicts (R2)

// ---------------------------------------------------------------------------
// Kernel 1: fold LN affine into the weights.
//   Wp[o][c] = bf16(W[o][c] * gamma[c]);  t1[o] = sum_c float(Wp[o][c]);
//   t2[o] = sum_c beta[c]*W[o][c] + b[o]
// ---------------------------------------------------------------------------
__global__ __launch_bounds__(128) void ppl_prep_kernel(const float* __restrict__ W,
                                                       const float* __restrict__ gamma,
                                                       const float* __restrict__ beta,
                                                       const float* __restrict__ bias,
                                                       __bf16* __restrict__ Wp,
                                                       float* __restrict__ t1,
                                                       float* __restrict__ t2) {
  const int o = blockIdx.x;
  const int t = threadIdx.x;
  const float* row = W + o * C_IN;
  float s1 = 0.f, s2 = 0.f;
  for (int c = t; c < C_IN; c += 128) {
    const float w = row[c];
    const __bf16 wq = (__bf16)(w * gamma[c]);
    Wp[o * C_IN + c] = wq;
    s1 += (float)wq;
    s2 += beta[c] * w;
  }
#pragma unroll
  for (int off = 32; off > 0; off >>= 1) {
    s1 += __shfl_down(s1, off);
    s2 += __shfl_down(s2, off);
  }
  __shared__ float red[2][2];
  if ((t & 63) == 0) { red[t >> 6][0] = s1; red[t >> 6][1] = s2; }
  __syncthreads();
  if (t == 0) {
    t1[o] = red[0][0] + red[1][0];
    t2[o] = red[0][1] + red[1][1] + bias[o];
  }
}

// fast GELU: tanh-form via sigmoid, err <= ~1e-3 (validated R2/R3: absmax unchanged)
__device__ __forceinline__ float gelu_fast(float v) {
  const float u = 0.7978845608028654f * v * __builtin_fmaf(0.044715f * v, v, 1.0f);
  const float e = __expf(-2.0f * u);
  return v * __builtin_amdgcn_rcpf(1.0f + e);
}

// ---------------------------------------------------------------------------
// Kernel 2: fused stats + GEMM + LN epilogue + GELU.
//   Block = 64 px x all 384 outs.  STAGING IS float4-ALONG-s: thread t owns
//   pixel quad 4*(t&15) and channels {64i + 4*(t>>4) + m}; 24 float4 loads
//   (1 KB/wave-instr) in two 12-deep chunks; bf16x4 b64 LDS writes; fp32
//   stats accumulated in regs, shfl_xor + LDS reduce.  k-loop: barrier-free,
//   32x32x16 MFMA, W' ping-pong prefetched from L2.  Epilogue: LN correction
//   + gelu_fast + f32x4 NCHW stores.
// ---------------------------------------------------------------------------
__global__ __launch_bounds__(256, 3) void ppl_fused_kernel(const float* __restrict__ x,
                                                           const __bf16* __restrict__ Wp,
                                                           const float* __restrict__ t1g,
                                                           const float* __restrict__ t2g,
                                                           float* __restrict__ out) {
  __shared__ __bf16 Xs[BP][LDK];
  __shared__ float sS[4][BP];
  __shared__ float sQ[4][BP];
  __shared__ float mu_s[BP];
  __shared__ float rs_s[BP];

  const int tid = threadIdx.x;
  const int w = tid >> 6;
  const int lane = tid & 63;
  const int q = tid & 15;    // pixel quad base 4q
  const int j = tid >> 4;    // channel group 0..15
  const int col = lane & 31;
  const int hi = lane >> 5;
  const int p0 = blockIdx.x * BP;
  const int b = p0 >> 12;
  const int s0 = p0 & 4095;
  const int ob = w * 96;

  const float* xq = x + (size_t)b * (C_IN * SPB) + s0 + 4 * q;

  // ---- staging: 24 float4 loads in 2 chunks of 12; pack + stats ----
  f32x4 LA[12], LB[12];
#pragma unroll
  for (int i = 0; i < 3; ++i)
#pragma unroll
    for (int m = 0; m < 4; ++m)
      LA[i * 4 + m] = *reinterpret_cast<const f32x4*>(xq + (size_t)(64 * i + 4 * j + m) * SPB);
#pragma unroll
  for (int i = 0; i < 3; ++i)
#pragma unroll
    for (int m = 0; m < 4; ++m)
      LB[i * 4 + m] = *reinterpret_cast<const f32x4*>(xq + (size_t)(64 * (i + 3) + 4 * j + m) * SPB);

  float ss[4] = {0.f, 0.f, 0.f, 0.f};
  float qq[4] = {0.f, 0.f, 0.f, 0.f};

#define PROCESS(L, ibase)                                                   \
  {                                                                         \
    _Pragma("unroll") for (int i = 0; i < 3; ++i) {                         \
      _Pragma("unroll") for (int r = 0; r < 4; ++r) {                       \
        const float f0 = L[i * 4 + 0][r];                                   \
        const float f1 = L[i * 4 + 1][r];                                   \
        const float f2 = L[i * 4 + 2][r];                                   \
        const float f3 = L[i * 4 + 3][r];                                   \
        ss[r] += (f0 + f1) + (f2 + f3);                                     \
        qq[r] += (f0 * f0 + f1 * f1) + (f2 * f2 + f3 * f3);                 \
        bf16x4 pk;                                                          \
        pk[0] = (__bf16)f0; pk[1] = (__bf16)f1;                             \
        pk[2] = (__bf16)f2; pk[3] = (__bf16)f3;                             \
        *reinterpret_cast<bf16x4*>(&Xs[4 * q + r][64 * ((ibase) + i) + 4 * j]) = pk; \
      }                                                                     \
    }                                                                       \
  }

  PROCESS(LA, 0)
  PROCESS(LB, 3)
#undef PROCESS

  // ---- stats reduce: shfl over j-within-wave, LDS over waves ----
#pragma unroll
  for (int r = 0; r < 4; ++r) {
    ss[r] += __shfl_xor(ss[r], 16);
    ss[r] += __shfl_xor(ss[r], 32);
    qq[r] += __shfl_xor(qq[r], 16);
    qq[r] += __shfl_xor(qq[r], 32);
  }
  if (lane < 16) {
#pragma unroll
    for (int r = 0; r < 4; ++r) {
      sS[w][4 * lane + r] = ss[r];
      sQ[w][4 * lane + r] = qq[r];
    }
  }
  __syncthreads();
  if (tid < BP) {
    const float st = sS[0][tid] + sS[1][tid] + sS[2][tid] + sS[3][tid];
    const float qt = sQ[0][tid] + sQ[1][tid] + sQ[2][tid] + sQ[3][tid];
    const float m = st * (1.0f / C_IN);
    mu_s[tid] = m;
    rs_s[tid] = rsqrtf(qt * (1.0f / C_IN) - m * m + 1e-5f);
  }
  __syncthreads();

  // ---- barrier-free k-loop, 32x32x16 MFMA, W ping-pong prefetch ----
  const __bf16* wp0 = Wp + (size_t)(ob + col) * C_IN + hi * 8;
  const __bf16* wp1 = wp0 + 32 * C_IN;
  const __bf16* wp2 = wp0 + 64 * C_IN;
  const __bf16* xs0 = &Xs[col][hi * 8];
  const __bf16* xs1 = &Xs[32 + col][hi * 8];

  f32x16 acc[2][3];
#pragma unroll
  for (int m = 0; m < 2; ++m)
#pragma unroll
    for (int n = 0; n < 3; ++n)
#pragma unroll
      for (int r = 0; r < 16; ++r) acc[m][n][r] = 0.f;

#define LOADB(dst, kk)                                     \
  {                                                        \
    dst[0] = *reinterpret_cast<const bf16x8*>(wp0 + (kk)); \
    dst[1] = *reinterpret_cast<const bf16x8*>(wp1 + (kk)); \
    dst[2] = *reinterpret_cast<const bf16x8*>(wp2 + (kk)); \
  }
#define STEP(bb, kk)                                                                    \
  {                                                                                     \
    const bf16x8 a0 = *reinterpret_cast<const bf16x8*>(xs0 + (kk));                     \
    const bf16x8 a1 = *reinterpret_cast<const bf16x8*>(xs1 + (kk));                     \
    acc[0][0] = __builtin_amdgcn_mfma_f32_32x32x16_bf16(a0, bb[0], acc[0][0], 0, 0, 0); \
    acc[0][1] = __builtin_amdgcn_mfma_f32_32x32x16_bf16(a0, bb[1], acc[0][1], 0, 0, 0); \
    acc[0][2] = __builtin_amdgcn_mfma_f32_32x32x16_bf16(a0, bb[2], acc[0][2], 0, 0, 0); \
    acc[1][0] = __builtin_amdgcn_mfma_f32_32x32x16_bf16(a1, bb[0], acc[1][0], 0, 0, 0); \
    acc[1][1] = __builtin_amdgcn_mfma_f32_32x32x16_bf16(a1, bb[1], acc[1][1], 0, 0, 0); \
    acc[1][2] = __builtin_amdgcn_mfma_f32_32x32x16_bf16(a1, bb[2], acc[1][2], 0, 0, 0); \
  }

  {
    bf16x8 bA[3], bB[3];
    LOADB(bA, 0);
#pragma unroll
    for (int it = 0; it < 12; ++it) {
      const int k = it * 32;
      LOADB(bB, k + 16);
      STEP(bA, k);
      if (it < 11) LOADB(bA, k + 32);
      STEP(bB, k + 16);
    }
  }
#undef LOADB
#undef STEP

  // ---- epilogue: LN correction + fast GELU + float4 NCHW stores ----
  const float t1v[3] = {t1g[ob + col], t1g[ob + 32 + col], t1g[ob + 64 + col]};
  const float t2v[3] = {t2g[ob + col], t2g[ob + 32 + col], t2g[ob + 64 + col]};
  float* outp = out + (((size_t)(b * C_OUT + ob + col)) << 12) + s0;

#pragma unroll
  for (int nf = 0; nf < 3; ++nf) {
    float* op = outp + ((size_t)nf << 17);  // += 32 out-channels
#pragma unroll
    for (int m = 0; m < 2; ++m) {
#pragma unroll
      for (int qd = 0; qd < 4; ++qd) {
        const int pr = m * 32 + qd * 8 + hi * 4;  // pixel base of this reg quad
        const f32x4 mu4 = *reinterpret_cast<const f32x4*>(&mu_s[pr]);
        const f32x4 rs4 = *reinterpret_cast<const f32x4*>(&rs_s[pr]);
        f32x4 y;
#pragma unroll
        for (int r = 0; r < 4; ++r) {
          const float val = rs4[r] * (acc[m][nf][qd * 4 + r] - mu4[r] * t1v[nf]) + t2v[nf];
          y[r] = gelu_fast(val);
        }
        *reinterpret_cast<f32x4*>(op + pr) = y;
      }
    }
  }
}

// ---------------------------------------------------------------------------
extern "C" void kernel_launch(void* const* d_in, const int* in_sizes, int n_in,
                              void* d_out, int out_size, void* d_ws, size_t ws_size,
                              hipStream_t stream) {
  const float* x = (const float*)d_in[0];
  const float* gamma = (const float*)d_in[1];
  const float* beta = (const float*)d_in[2];
  const float* W = (const float*)d_in[3];
  const float* bias = (const float*)d_in[4];
  float* out = (float*)d_out;

  __bf16* Wp = (__bf16*)d_ws;                    // 384*384 bf16
  float* t1 = (float*)(Wp + C_OUT * C_IN);       // 384 floats
  float* t2 = t1 + C_OUT;                        // 384 floats

  ppl_prep_kernel<<<C_OUT, 128, 0, stream>>>(W, gamma, beta, bias, Wp, t1, t2);
  ppl_fused_kernel<<<NPIX / BP, 256, 0, stream>>>(x, Wp, t1, t2, out);
}